// Round 8
// baseline (309.385 us; speedup 1.0000x reference)
//
#include <hip/hip_runtime.h>
#include <hip/hip_bf16.h>

typedef __attribute__((ext_vector_type(8))) __bf16 bf16x8;
typedef __attribute__((ext_vector_type(4))) __bf16 bf16x4;
typedef __attribute__((ext_vector_type(4))) float f32x4;
typedef __attribute__((ext_vector_type(16))) float f32x16;

#define T_TOK 2048
#define NH 32
#define NKV 4
#define HD 128
#define HID 2048
#define QKV_N 5120   // (32 + 2*4) * 128
#define QSZ 4096     // 32*128
#define KOFF 4096
#define VOFF 4608
#define ATT_N 4096

#define GLOAD_LDS16(g, l)                                              \
  __builtin_amdgcn_global_load_lds(                                    \
      (const __attribute__((address_space(1))) void*)(g),              \
      (__attribute__((address_space(3))) void*)(l), 16, 0, 0)

// ---------------- cast fp32 -> bf16 (row-major, vectorized) ----------------
__global__ __launch_bounds__(256) void cast_f32_bf16(const float* __restrict__ in,
                                                     __bf16* __restrict__ out, int n4) {
  int i = blockIdx.x * 256 + threadIdx.x;
  if (i < n4) {
    float4 v = reinterpret_cast<const float4*>(in)[i];
    bf16x4 o;
    o[0] = (__bf16)v.x; o[1] = (__bf16)v.y; o[2] = (__bf16)v.z; o[3] = (__bf16)v.w;
    reinterpret_cast<bf16x4*>(out)[i] = o;
  }
}

// ------------- cast + transpose: in fp32 [R][C] -> out bf16 [C][R] ---------
__global__ __launch_bounds__(256) void transpose_cast(const float* __restrict__ in,
                                                      __bf16* __restrict__ out,
                                                      int R, int C) {
  __shared__ __attribute__((aligned(16))) __bf16 tile[64][72];  // [c][r]
  const int c0 = blockIdx.x * 64;
  const int r0 = blockIdx.y * 64;
  const int ca = (threadIdx.x & 15) * 4;
  const int ra = (threadIdx.x >> 4) * 4;
  float4 v[4];
#pragma unroll
  for (int i = 0; i < 4; ++i)
    v[i] = *reinterpret_cast<const float4*>(&in[(size_t)(r0 + ra + i) * C + c0 + ca]);
#pragma unroll
  for (int j = 0; j < 4; ++j) {
    bf16x4 o;
#pragma unroll
    for (int i = 0; i < 4; ++i) o[i] = (__bf16)(((const float*)&v[i])[j]);
    *reinterpret_cast<bf16x4*>(&tile[ca + j][ra]) = o;
  }
  __syncthreads();
#pragma unroll
  for (int i = 0; i < 2; ++i) {
    int c = i * 32 + (threadIdx.x >> 3);
    int r8 = (threadIdx.x & 7) * 8;
    bf16x8 o = *reinterpret_cast<const bf16x8*>(&tile[c][r8]);
    *reinterpret_cast<bf16x8*>(&out[(size_t)(c0 + c) * R + r0 + r8]) = o;
  }
}

// ---- transpose V section of qkv: [t][kvh*128+d] -> vt[kvh][d][t] (bf16) ----
__global__ __launch_bounds__(256) void v_transpose(const __bf16* __restrict__ qkv,
                                                   __bf16* __restrict__ vt) {
  __shared__ __bf16 tile[64][72];
  int t0 = blockIdx.x * 64;
  int d0 = blockIdx.y * 64;
  int kvh = blockIdx.z;
  int tx = threadIdx.x & 63;
  int ty = threadIdx.x >> 6;
#pragma unroll
  for (int i = 0; i < 64; i += 4)
    tile[ty + i][tx] = qkv[(size_t)(t0 + ty + i) * QKV_N + VOFF + kvh * HD + d0 + tx];
  __syncthreads();
#pragma unroll
  for (int i = 0; i < 64; i += 4)
    vt[((size_t)kvh * HD + d0 + ty + i) * T_TOK + t0 + tx] = tile[tx][ty + i];
}

// ====== GEMM, depth-4 pipeline: C[M][N] = A[M][K]*B^T (B stored [N][K]) ====
// 128x128 tile, BK=32, 5 rotating LDS buffers (80KB), single barrier/K-step,
// counted vmcnt(12) steady state (loads span 3 compute phases ~ HBM latency),
// T2 XOR-swizzled LDS via pre-swizzled global source (rule #21).
template <int OUTF32>
__global__ __launch_bounds__(256) void gemm_p5(const __bf16* __restrict__ A,
                                               const __bf16* __restrict__ B,
                                               void* __restrict__ Cp,
                                               int M, int N, int K, int nbx) {
  __shared__ __attribute__((aligned(16))) __bf16 As[5][128][32];
  __shared__ __attribute__((aligned(16))) __bf16 Bs[5][128][32];
  const int tid = threadIdx.x;
  const int lane = tid & 63;
  const int wave = tid >> 6;
  const int la = lane & 15;
  const int lb = lane >> 4;
  const int wr = (wave >> 1) * 64;
  const int wc = (wave & 1) * 64;

  // bijective XCD swizzle (grid size divisible by 8)
  const int nwg = gridDim.x;
  const int cpx = nwg >> 3;
  const int swz = ((int)blockIdx.x & 7) * cpx + ((int)blockIdx.x >> 3);
  const int bx = swz % nbx;
  const int by = swz / nbx;
  const int rowA0 = by * 128;
  const int rowB0 = bx * 128;

  // staging: lane L covers row srow = wave*16 + L/4, 16B col (L&3)*16, with
  // the col PRE-SWIZZLED in the global source so the swizzled layout lands
  // in linear LDS (gload_lds dest = base + lane*16).
  const int srow = wave * 16 + (lane >> 2);
  const int scol = (((lane & 3) * 16) ^ (((lane >> 2) & 3) << 4)) >> 1;  // elems
  const __bf16* Asrc0 = &A[(size_t)(rowA0 + srow) * K + scol];
  const __bf16* Asrc1 = &A[(size_t)(rowA0 + 64 + srow) * K + scol];
  const __bf16* Bsrc0 = &B[(size_t)(rowB0 + srow) * K + scol];
  const __bf16* Bsrc1 = &B[(size_t)(rowB0 + 64 + srow) * K + scol];

#define STAGEG(b, k0)                                            \
  do {                                                           \
    GLOAD_LDS16(Asrc0 + (k0), &As[b][wave * 16][0]);             \
    GLOAD_LDS16(Asrc1 + (k0), &As[b][64 + wave * 16][0]);        \
    GLOAD_LDS16(Bsrc0 + (k0), &Bs[b][wave * 16][0]);             \
    GLOAD_LDS16(Bsrc1 + (k0), &Bs[b][64 + wave * 16][0]);        \
  } while (0)

  f32x4 acc[4][4] = {};

  const int nt = K >> 5;   // 64 or 128 here
  STAGEG(0, 0);
  STAGEG(1, 32);
  STAGEG(2, 64);
  STAGEG(3, 96);
  asm volatile("s_waitcnt vmcnt(12)" ::: "memory");   // tile 0 landed
  __builtin_amdgcn_s_barrier();
  __builtin_amdgcn_sched_barrier(0);

  // fragment read col swizzle: row&3 == la&3 for all m (wr, m*16 mult of 4)
  const int rdswz = (lb * 16) ^ ((la & 3) << 4);

  int cur = 0, stg = 4;
  for (int t = 0; t < nt; ++t) {
    if (t + 4 < nt) {
      STAGEG(stg, (t + 4) * 32);   // issue early; 3 compute phases to land
    }

    const char* Ab = (const char*)&As[cur][0][0];
    const char* Bb = (const char*)&Bs[cur][0][0];
    bf16x8 af[4], bfr[4];
#pragma unroll
    for (int m = 0; m < 4; ++m)
      af[m] = *reinterpret_cast<const bf16x8*>(Ab + (wr + m * 16 + la) * 64 + rdswz);
#pragma unroll
    for (int n = 0; n < 4; ++n)
      bfr[n] = *reinterpret_cast<const bf16x8*>(Bb + (wc + n * 16 + la) * 64 + rdswz);
    __builtin_amdgcn_s_setprio(1);
#pragma unroll
    for (int m = 0; m < 4; ++m)
#pragma unroll
      for (int n = 0; n < 4; ++n)
        acc[m][n] = __builtin_amdgcn_mfma_f32_16x16x32_bf16(af[m], bfr[n], acc[m][n], 0, 0, 0);
    __builtin_amdgcn_s_setprio(0);

    const int rem = nt - 1 - t;
    if (rem >= 4) {
      asm volatile("s_waitcnt vmcnt(12)" ::: "memory");  // t+1 landed; 3 in flight
    } else if (rem == 3) {
      asm volatile("s_waitcnt vmcnt(8)" ::: "memory");
    } else if (rem == 2) {
      asm volatile("s_waitcnt vmcnt(4)" ::: "memory");
    } else if (rem == 1) {
      asm volatile("s_waitcnt vmcnt(0)" ::: "memory");
    }
    if (rem) {
      __builtin_amdgcn_sched_barrier(0);
      __builtin_amdgcn_s_barrier();     // single barrier per K-step
      __builtin_amdgcn_sched_barrier(0);
    }
    cur = (cur == 4) ? 0 : cur + 1;
    stg = (stg == 4) ? 0 : stg + 1;
  }
#undef STAGEG

#pragma unroll
  for (int m = 0; m < 4; ++m) {
#pragma unroll
    for (int n = 0; n < 4; ++n) {
#pragma unroll
      for (int r = 0; r < 4; ++r) {
        int row = rowA0 + wr + m * 16 + lb * 4 + r;
        int col = rowB0 + wc + n * 16 + la;
        if (OUTF32)
          reinterpret_cast<float*>(Cp)[(size_t)row * N + col] = acc[m][n][r];
        else
          reinterpret_cast<__bf16*>(Cp)[(size_t)row * N + col] = (__bf16)acc[m][n][r];
      }
    }
  }
}

// ---------------- RoPE cos/sin table: tab[t][0..63]=cos, [64..127]=sin -----
__global__ __launch_bounds__(64) void rope_table(const int* __restrict__ positions,
                                                 float* __restrict__ tab) {
  const int t = blockIdx.x;
  const int d = threadIdx.x;
  float freq = exp2f(-(float)d * 0.20762050593046015f);
  float fr = (float)positions[t] * freq;
  float c, s;
  sincosf(fr, &s, &c);
  tab[t * 128 + d] = c;
  tab[t * 128 + 64 + d] = s;
}

// ------------- RMSNorm + RoPE in-place on q/k rows of qkv buffer -----------
__global__ __launch_bounds__(128) void norm_rope(__bf16* __restrict__ qkv,
                                                 const float* __restrict__ tab,
                                                 const float* __restrict__ qw,
                                                 const float* __restrict__ kw) {
  const int t = blockIdx.x;
  const int head = blockIdx.y;
  const bool is_q = head < NH;
  const int col = is_q ? head * HD : KOFF + (head - NH) * HD;
  __bf16* row = qkv + (size_t)t * QKV_N + col;
  const int d = threadIdx.x;
  float x = (float)row[d];
  float ss = x * x;
#pragma unroll
  for (int mm = 1; mm < 64; mm <<= 1) ss += __shfl_xor(ss, mm);
  __shared__ float red[2];
  __shared__ float yl[128];
  if ((d & 63) == 0) red[d >> 6] = ss;
  __syncthreads();
  float var = (red[0] + red[1]) * (1.0f / 128.0f);
  float sc = rsqrtf(var + 1e-6f);
  const float* wv = is_q ? qw : kw;
  yl[d] = x * sc * wv[d];
  __syncthreads();
  if (d < 64) {
    float x1 = yl[d], x2 = yl[d + 64];
    float c = tab[t * 128 + d];
    float sn = tab[t * 128 + 64 + d];
    row[d] = (__bf16)(x1 * c - x2 * sn);
    row[d + 64] = (__bf16)(x2 * c + x1 * sn);
  }
}

// ===== flash attention, swapped-QK^T 32x32 structure (unchanged from R7) ====
__device__ __forceinline__ uint32_t pkbf(float a, float b) {
  union { __bf16 h; unsigned short u; } x, y;
  x.h = (__bf16)a;
  y.h = (__bf16)b;
  return (uint32_t)x.u | ((uint32_t)y.u << 16);
}

__global__ __launch_bounds__(256, 2) void flash_attn5(const __bf16* __restrict__ qkv,
                                                      const __bf16* __restrict__ vt,
                                                      __bf16* __restrict__ attn) {
  __shared__ __attribute__((aligned(16))) __bf16 lds[32768];

  const int tid = threadIdx.x;
  const int lane = tid & 63;
  const int wave = tid >> 6;     // 0..3
  const int q5 = lane & 31;
  const int hi = lane >> 5;
  const int yy = blockIdx.x;     // 0..7
  const int kvh = yy >> 1;
  const int h = kvh * 8 + (yy & 1) * 4 + wave;
  const __bf16* Kbase = qkv + KOFF + kvh * HD;
  const __bf16* Vbase = vt + (size_t)kvh * HD * T_TOK;

  const int qt = 63 - (int)blockIdx.y;
  const int qb = qt * 32;
  const int qrow = qb + q5;
  const int nt = (qb + 32 + 63) >> 6;

  const float qscale = 0.088388347648318447f * 1.4426950408889634f;

  bf16x8 qf[8];
  {
    const __bf16* Qp = qkv + (size_t)(qb + q5) * QKV_N + h * HD + hi * 8;
#pragma unroll
    for (int k0 = 0; k0 < 8; ++k0) {
      bf16x8 q = *reinterpret_cast<const bf16x8*>(Qp + k0 * 16);
#pragma unroll
      for (int j = 0; j < 8; ++j) q[j] = (__bf16)((float)q[j] * qscale);
      qf[k0] = q;
    }
  }

  const int kc = (lane & 15) * 16;
  const int vc = (lane & 7) * 16;

#define STAGE5(b, kv00)                                                         \
  do {                                                                          \
    __bf16* kdst = lds + (b) * 8192;                                            \
    __bf16* vdst = lds + 16384 + (b) * 8192;                                    \
    _Pragma("unroll")                                                           \
    for (int i = 0; i < 4; ++i) {                                               \
      int kr = wave * 16 + i * 4 + (lane >> 4);                                 \
      int ksc = (kc ^ ((kr & 15) << 4)) >> 1;                                   \
      GLOAD_LDS16(Kbase + (size_t)((kv00) + kr) * QKV_N + ksc,                  \
                  kdst + (wave * 16 + i * 4) * 128);                            \
      int vr = wave * 32 + i * 8 + (lane >> 3);                                 \
      int vsc = (vc ^ ((vr & 7) << 4)) >> 1;                                    \
      GLOAD_LDS16(Vbase + (size_t)vr * T_TOK + (kv00) + vsc,                    \
                  vdst + (wave * 32 + i * 8) * 64);                             \
    }                                                                           \
  } while (0)

  f32x16 acc0 = {}, acc1 = {}, acc2 = {}, acc3 = {};
  float mrow = -1e30f, lrow = 0.0f;

  STAGE5(0, 0);

  int cur = 0;
  for (int t = 0; t < nt; ++t) {
    const int kv0 = t * 64;
    __builtin_amdgcn_s_barrier();
    __builtin_amdgcn_sched_barrier(0);
    if (t + 1 < nt) {
      STAGE5(cur ^ 1, kv0 + 64);
      asm volatile("s_waitcnt vmcnt(8)" ::: "memory");
    } else {
      asm volatile("s_waitcnt vmcnt(0)" ::: "memory");
    }
    __builtin_amdgcn_s_barrier();
    __builtin_amdgcn_sched_barrier(0);

    const char* Kt = (const char*)(lds + cur * 8192);
    const char* Vt = (const char*)(lds + 16384 + cur * 8192);

    f32x16 st0 = {}, st1 = {};
    __builtin_amdgcn_s_setprio(1);
#pragma unroll
    for (int k0 = 0; k0 < 8; ++k0) {
      int cS = (k0 * 32 + hi * 16) ^ ((q5 & 15) << 4);
      bf16x8 a0 = *reinterpret_cast<const bf16x8*>(Kt + q5 * 256 + cS);
      bf16x8 a1 = *reinterpret_cast<const bf16x8*>(Kt + (32 + q5) * 256 + cS);
      st0 = __builtin_amdgcn_mfma_f32_32x32x16_bf16(a0, qf[k0], st0, 0, 0, 0);
      st1 = __builtin_amdgcn_mfma_f32_32x32x16_bf16(a1, qf[k0], st1, 0, 0, 0);
    }
    __builtin_amdgcn_s_setprio(0);

    if (!(kv0 + 63 <= qb)) {
#pragma unroll
      for (int r = 0; r < 16; ++r) {
        int kp = kv0 + (r & 3) + 8 * (r >> 2) + 4 * hi;
        if (kp > qrow) st0[r] = -1e30f;
        if (kp + 32 > qrow) st1[r] = -1e30f;
      }
    }
    float mx = -1e30f;
#pragma unroll
    for (int r = 0; r < 16; ++r) mx = fmaxf(mx, fmaxf(st0[r], st1[r]));
    mx = fmaxf(mx, __shfl_xor(mx, 32));
    if (__any(mx > mrow + 8.0f)) {
      float mnew = fmaxf(mrow, mx);
      float corr = exp2f(mrow - mnew);
      lrow *= corr;
      acc0 *= corr; acc1 *= corr; acc2 *= corr; acc3 *= corr;
      mrow = mnew;
    }
    float ps = 0.0f;
#pragma unroll
    for (int r = 0; r < 16; ++r) {
      float p0 = exp2f(st0[r] - mrow);
      float p1 = exp2f(st1[r] - mrow);
      ps += p0 + p1;
      st0[r] = p0;
      st1[r] = p1;
    }
    ps += __shfl_xor(ps, 32);
    lrow += ps;

    uint32_t W0[8], W1[8];
#pragma unroll
    for (int m = 0; m < 8; ++m) {
      W0[m] = pkbf(st0[2 * m], st0[2 * m + 1]);
      W1[m] = pkbf(st1[2 * m], st1[2 * m + 1]);
    }

    const bool hib = (hi != 0);
#pragma unroll
    for (int ks = 0; ks < 4; ++ks) {
      const int j = 4 * (ks & 1);
      uint32_t wj0, wj1, wj2, wj3;
      if (ks < 2) { wj0 = W0[j]; wj1 = W0[j + 1]; wj2 = W0[j + 2]; wj3 = W0[j + 3]; }
      else        { wj0 = W1[j]; wj1 = W1[j + 1]; wj2 = W1[j + 2]; wj3 = W1[j + 3]; }
      uint32_t keepA = hib ? wj2 : wj0;
      uint32_t keepB = hib ? wj3 : wj1;
      uint32_t sendA = hib ? wj0 : wj2;
      uint32_t sendB = hib ? wj1 : wj3;
      uint32_t recvA = (uint32_t)__shfl_xor((int)sendA, 32);
      uint32_t recvB = (uint32_t)__shfl_xor((int)sendB, 32);
      union { uint32_t u[4]; bf16x8 v; } fr;
      fr.u[0] = hib ? recvA : keepA;
      fr.u[1] = hib ? recvB : keepB;
      fr.u[2] = hib ? keepA : recvA;
      fr.u[3] = hib ? keepB : recvB;
      const int cV = (ks * 32 + hi * 16) ^ ((q5 & 7) << 4);
      __builtin_amdgcn_s_setprio(1);
      bf16x8 v0 = *reinterpret_cast<const bf16x8*>(Vt + (0 * 32 + q5) * 128 + cV);
      acc0 = __builtin_amdgcn_mfma_f32_32x32x16_bf16(v0, fr.v, acc0, 0, 0, 0);
      bf16x8 v1 = *reinterpret_cast<const bf16x8*>(Vt + (1 * 32 + q5) * 128 + cV);
      acc1 = __builtin_amdgcn_mfma_f32_32x32x16_bf16(v1, fr.v, acc1, 0, 0, 0);
      bf16x8 v2 = *reinterpret_cast<const bf16x8*>(Vt + (2 * 32 + q5) * 128 + cV);
      acc2 = __builtin_amdgcn_mfma_f32_32x32x16_bf16(v2, fr.v, acc2, 0, 0, 0);
      bf16x8 v3 = *reinterpret_cast<const bf16x8*>(Vt + (3 * 32 + q5) * 128 + cV);
      acc3 = __builtin_amdgcn_mfma_f32_32x32x16_bf16(v3, fr.v, acc3, 0, 0, 0);
      __builtin_amdgcn_s_setprio(0);
    }
    cur ^= 1;
  }

  __syncthreads();
  {
    char* ob = (char*)lds + wave * 8192;
    float inv = 1.0f / lrow;
    const int swzE = (q5 & 15) << 4;
#pragma unroll
    for (int dt = 0; dt < 4; ++dt) {
      f32x16 a = dt == 0 ? acc0 : dt == 1 ? acc1 : dt == 2 ? acc2 : acc3;
#pragma unroll
      for (int t4 = 0; t4 < 4; ++t4) {
        uint2 wv;
        wv.x = pkbf(a[4 * t4] * inv, a[4 * t4 + 1] * inv);
        wv.y = pkbf(a[4 * t4 + 2] * inv, a[4 * t4 + 3] * inv);
        int d2 = (dt * 32 + 8 * t4 + 4 * hi) * 2;
        *reinterpret_cast<uint2*>(ob + q5 * 256 + (d2 ^ swzE)) = wv;
      }
    }
#pragma unroll
    for (int rr = 0; rr < 8; ++rr) {
      int idx = rr * 64 + lane;
      int q = idx >> 4;
      int cc = (idx & 15) * 16;
      bf16x8 o = *reinterpret_cast<const bf16x8*>(ob + q * 256 + (cc ^ ((q & 15) << 4)));
      *reinterpret_cast<bf16x8*>(&attn[(size_t)(qb + q) * ATT_N + h * HD + (cc >> 1)]) = o;
    }
  }
}

extern "C" void kernel_launch(void* const* d_in, const int* in_sizes, int n_in,
                              void* d_out, int out_size, void* d_ws, size_t ws_size,
                              hipStream_t stream) {
  const float* hs   = (const float*)d_in[0];
  const int*   pos  = (const int*)d_in[1];
  const float* wqkv = (const float*)d_in[2];
  const float* wo   = (const float*)d_in[3];
  const float* qw   = (const float*)d_in[4];
  const float* kw   = (const float*)d_in[5];
  float* out = (float*)d_out;

  char* p = (char*)d_ws;
  __bf16* hsb   = (__bf16*)p; p += (size_t)T_TOK * HID * 2;
  __bf16* wqkvT = (__bf16*)p; p += (size_t)QKV_N * HID * 2;
  __bf16* woT   = (__bf16*)p; p += (size_t)HID * QSZ * 2;
  __bf16* qkvb  = (__bf16*)p; p += (size_t)T_TOK * QKV_N * 2;
  __bf16* attnb = (__bf16*)p; p += (size_t)T_TOK * QSZ * 2;
  __bf16* vtb   = (__bf16*)p; p += (size_t)NKV * HD * T_TOK * 2;
  float*  ropet = (float*)p;  p += (size_t)T_TOK * HD * 4;

  cast_f32_bf16<<<(T_TOK * HID / 4) / 256, 256, 0, stream>>>(hs, hsb, T_TOK * HID / 4);
  transpose_cast<<<dim3(QKV_N / 64, HID / 64), 256, 0, stream>>>(wqkv, wqkvT, HID, QKV_N);
  transpose_cast<<<dim3(HID / 64, QSZ / 64), 256, 0, stream>>>(wo, woT, QSZ, HID);
  rope_table<<<T_TOK, 64, 0, stream>>>(pos, ropet);
  // QKV projection: grid flattened 40*16 = 640 (div by 8)
  gemm_p5<0><<<(QKV_N / 128) * (T_TOK / 128), 256, 0, stream>>>(
      hsb, wqkvT, qkvb, T_TOK, QKV_N, HID, QKV_N / 128);
  norm_rope<<<dim3(T_TOK, NH + NKV), 128, 0, stream>>>(qkvb, ropet, qw, kw);
  v_transpose<<<dim3(T_TOK / 64, HD / 64, NKV), 256, 0, stream>>>(qkvb, vtb);
  flash_attn5<<<dim3(8, 64), 256, 0, stream>>>(qkvb, vtb, attnb);
  // O projection: grid 16*16 = 256 (div by 8)
  gemm_p5<1><<<(HID / 128) * (T_TOK / 128), 256, 0, stream>>>(
      attnb, woT, out, T_TOK, HID, QSZ, HID / 128);
}

// Round 9
// 250.287 us; speedup vs baseline: 1.2361x; 1.2361x over previous
//
#include <hip/hip_runtime.h>
#include <hip/hip_bf16.h>

typedef __attribute__((ext_vector_type(8))) __bf16 bf16x8;
typedef __attribute__((ext_vector_type(4))) __bf16 bf16x4;
typedef __attribute__((ext_vector_type(4))) float f32x4;
typedef __attribute__((ext_vector_type(16))) float f32x16;

#define T_TOK 2048
#define NH 32
#define NKV 4
#define HD 128
#define HID 2048
#define QKV_N 5120   // (32 + 2*4) * 128
#define QSZ 4096     // 32*128
#define KOFF 4096
#define VOFF 4608
#define ATT_N 4096

#define GLOAD_LDS16(g, l)                                              \
  __builtin_amdgcn_global_load_lds(                                    \
      (const __attribute__((address_space(1))) void*)(g),              \
      (__attribute__((address_space(3))) void*)(l), 16, 0, 0)

// ---------------- cast fp32 -> bf16 (row-major, vectorized) ----------------
__global__ __launch_bounds__(256) void cast_f32_bf16(const float* __restrict__ in,
                                                     __bf16* __restrict__ out, int n4) {
  int i = blockIdx.x * 256 + threadIdx.x;
  if (i < n4) {
    float4 v = reinterpret_cast<const float4*>(in)[i];
    bf16x4 o;
    o[0] = (__bf16)v.x; o[1] = (__bf16)v.y; o[2] = (__bf16)v.z; o[3] = (__bf16)v.w;
    reinterpret_cast<bf16x4*>(out)[i] = o;
  }
}

// ------------- cast + transpose: in fp32 [R][C] -> out bf16 [C][R] ---------
__global__ __launch_bounds__(256) void transpose_cast(const float* __restrict__ in,
                                                      __bf16* __restrict__ out,
                                                      int R, int C) {
  __shared__ __attribute__((aligned(16))) __bf16 tile[64][72];  // [c][r]
  const int c0 = blockIdx.x * 64;
  const int r0 = blockIdx.y * 64;
  const int ca = (threadIdx.x & 15) * 4;
  const int ra = (threadIdx.x >> 4) * 4;
  float4 v[4];
#pragma unroll
  for (int i = 0; i < 4; ++i)
    v[i] = *reinterpret_cast<const float4*>(&in[(size_t)(r0 + ra + i) * C + c0 + ca]);
#pragma unroll
  for (int j = 0; j < 4; ++j) {
    bf16x4 o;
#pragma unroll
    for (int i = 0; i < 4; ++i) o[i] = (__bf16)(((const float*)&v[i])[j]);
    *reinterpret_cast<bf16x4*>(&tile[ca + j][ra]) = o;
  }
  __syncthreads();
#pragma unroll
  for (int i = 0; i < 2; ++i) {
    int c = i * 32 + (threadIdx.x >> 3);
    int r8 = (threadIdx.x & 7) * 8;
    bf16x8 o = *reinterpret_cast<const bf16x8*>(&tile[c][r8]);
    *reinterpret_cast<bf16x8*>(&out[(size_t)(c0 + c) * R + r0 + r8]) = o;
  }
}

// ---- transpose V section of qkv: [t][kvh*128+d] -> vt[kvh][d][t] (bf16) ----
__global__ __launch_bounds__(256) void v_transpose(const __bf16* __restrict__ qkv,
                                                   __bf16* __restrict__ vt) {
  __shared__ __bf16 tile[64][72];
  int t0 = blockIdx.x * 64;
  int d0 = blockIdx.y * 64;
  int kvh = blockIdx.z;
  int tx = threadIdx.x & 63;
  int ty = threadIdx.x >> 6;
#pragma unroll
  for (int i = 0; i < 64; i += 4)
    tile[ty + i][tx] = qkv[(size_t)(t0 + ty + i) * QKV_N + VOFF + kvh * HD + d0 + tx];
  __syncthreads();
#pragma unroll
  for (int i = 0; i < 64; i += 4)
    vt[((size_t)kvh * HD + d0 + ty + i) * T_TOK + t0 + tx] = tile[tx][ty + i];
}

// ====== GEMM v9: C[M][N] = A[M][K]*B^T, optional split-K ===================
// 128x128 tile, BK=32, 3 rotating LDS buffers (48KB = 3 blocks/CU), single
// barrier/K-step, counted vmcnt, 4-way read swizzle (pre-swizzled source),
// by-fast XCD mapping (B-panel stays L2-hot, A streams).
// OUTF32=0: bf16 store to Cp[M][N]. OUTF32=1: fp32 store to
// ((float*)Cp) + ks*M*N (split-K partials).
template <int OUTF32>
__global__ __launch_bounds__(256) void gemm_v9(const __bf16* __restrict__ A,
                                               const __bf16* __restrict__ B,
                                               void* __restrict__ Cp,
                                               int M, int N, int Ktot, int KS,
                                               int nby, int nks) {
  __shared__ __attribute__((aligned(16))) __bf16 As[3][128][32];
  __shared__ __attribute__((aligned(16))) __bf16 Bs[3][128][32];
  const int tid = threadIdx.x;
  const int lane = tid & 63;
  const int wave = tid >> 6;
  const int la = lane & 15;
  const int lb = lane >> 4;
  const int wr = (wave >> 1) * 64;
  const int wc = (wave & 1) * 64;

  // bijective XCD swizzle (grid size divisible by 8)
  const int nwg = gridDim.x;
  const int cpx = nwg >> 3;
  const int swz = ((int)blockIdx.x & 7) * cpx + ((int)blockIdx.x >> 3);
  const int ks = swz % nks;
  const int t2 = swz / nks;
  const int by = t2 % nby;        // M-tile fastest -> B panel L2-hot
  const int bx = t2 / nby;
  const int rowA0 = by * 128;
  const int rowB0 = bx * 128;
  const int k00 = ks * KS;

  // staging: lane L -> row wave*16 + L/4, 16B chunk (L&3), source col
  // PRE-SWIZZLED so swizzled layout lands in linear LDS (rule #21).
  const int srow = wave * 16 + (lane >> 2);
  const int scol = (((lane & 3) * 16) ^ (((lane >> 2) & 3) << 4)) >> 1;  // elems
  const __bf16* Asrc0 = &A[(size_t)(rowA0 + srow) * Ktot + k00 + scol];
  const __bf16* Asrc1 = &A[(size_t)(rowA0 + 64 + srow) * Ktot + k00 + scol];
  const __bf16* Bsrc0 = &B[(size_t)(rowB0 + srow) * Ktot + k00 + scol];
  const __bf16* Bsrc1 = &B[(size_t)(rowB0 + 64 + srow) * Ktot + k00 + scol];

#define STAGEG(b, k0)                                            \
  do {                                                           \
    GLOAD_LDS16(Asrc0 + (k0), &As[b][wave * 16][0]);             \
    GLOAD_LDS16(Asrc1 + (k0), &As[b][64 + wave * 16][0]);        \
    GLOAD_LDS16(Bsrc0 + (k0), &Bs[b][wave * 16][0]);             \
    GLOAD_LDS16(Bsrc1 + (k0), &Bs[b][64 + wave * 16][0]);        \
  } while (0)

  f32x4 acc[4][4] = {};

  const int nt = KS >> 5;
  STAGEG(0, 0);
  STAGEG(1, 32);
  asm volatile("s_waitcnt vmcnt(4)" ::: "memory");   // tile 0 landed
  __builtin_amdgcn_s_barrier();
  __builtin_amdgcn_sched_barrier(0);

  // fragment read col swizzle: row&3 == la&3 (wr, m*16 multiples of 4)
  const int rdswz = (lb * 16) ^ ((la & 3) << 4);

  int cur = 0, stg = 2;
  for (int t = 0; t < nt; ++t) {
    if (t + 2 < nt) {
      STAGEG(stg, (t + 2) * 32);   // issue early; lands during this MFMA phase
    }

    const char* Ab = (const char*)&As[cur][0][0];
    const char* Bb = (const char*)&Bs[cur][0][0];
    bf16x8 af[4], bfr[4];
#pragma unroll
    for (int m = 0; m < 4; ++m)
      af[m] = *reinterpret_cast<const bf16x8*>(Ab + (wr + m * 16 + la) * 64 + rdswz);
#pragma unroll
    for (int n = 0; n < 4; ++n)
      bfr[n] = *reinterpret_cast<const bf16x8*>(Bb + (wc + n * 16 + la) * 64 + rdswz);
    __builtin_amdgcn_s_setprio(1);
#pragma unroll
    for (int m = 0; m < 4; ++m)
#pragma unroll
      for (int n = 0; n < 4; ++n)
        acc[m][n] = __builtin_amdgcn_mfma_f32_16x16x32_bf16(af[m], bfr[n], acc[m][n], 0, 0, 0);
    __builtin_amdgcn_s_setprio(0);

    const int rem = nt - 1 - t;
    if (rem >= 2) {
      asm volatile("s_waitcnt vmcnt(4)" ::: "memory");  // t+1 landed, t+2 in flight
    } else if (rem == 1) {
      asm volatile("s_waitcnt vmcnt(0)" ::: "memory");
    }
    if (rem) {
      __builtin_amdgcn_sched_barrier(0);
      __builtin_amdgcn_s_barrier();     // single barrier per K-step
      __builtin_amdgcn_sched_barrier(0);
    }
    cur = (cur == 2) ? 0 : cur + 1;
    stg = (stg == 2) ? 0 : stg + 1;
  }
#undef STAGEG

#pragma unroll
  for (int m = 0; m < 4; ++m) {
#pragma unroll
    for (int n = 0; n < 4; ++n) {
#pragma unroll
      for (int r = 0; r < 4; ++r) {
        int row = rowA0 + wr + m * 16 + lb * 4 + r;
        int col = rowB0 + wc + n * 16 + la;
        if (OUTF32) {
          float* pp = (float*)Cp + (size_t)ks * M * N;
          pp[(size_t)row * N + col] = acc[m][n][r];
        } else {
          reinterpret_cast<__bf16*>(Cp)[(size_t)row * N + col] = (__bf16)acc[m][n][r];
        }
      }
    }
  }
}

// -------- split-K reduce: out[i] = p0[i] + p1[i] (fp32, vectorized) --------
__global__ __launch_bounds__(256) void reduce2_f32(const float* __restrict__ pp,
                                                   float* __restrict__ out, int n4) {
  int i = blockIdx.x * 256 + threadIdx.x;
  if (i < n4) {
    float4 a = reinterpret_cast<const float4*>(pp)[i];
    float4 b = reinterpret_cast<const float4*>(pp + (size_t)HID * T_TOK)[i];
    float4 o;
    o.x = a.x + b.x; o.y = a.y + b.y; o.z = a.z + b.z; o.w = a.w + b.w;
    reinterpret_cast<float4*>(out)[i] = o;
  }
}

// ---------------- RoPE cos/sin table: tab[t][0..63]=cos, [64..127]=sin -----
__global__ __launch_bounds__(64) void rope_table(const int* __restrict__ positions,
                                                 float* __restrict__ tab) {
  const int t = blockIdx.x;
  const int d = threadIdx.x;
  float freq = exp2f(-(float)d * 0.20762050593046015f);
  float fr = (float)positions[t] * freq;
  float c, s;
  sincosf(fr, &s, &c);
  tab[t * 128 + d] = c;
  tab[t * 128 + 64 + d] = s;
}

// ------------- RMSNorm + RoPE in-place on q/k rows of qkv buffer -----------
__global__ __launch_bounds__(128) void norm_rope(__bf16* __restrict__ qkv,
                                                 const float* __restrict__ tab,
                                                 const float* __restrict__ qw,
                                                 const float* __restrict__ kw) {
  const int t = blockIdx.x;
  const int head = blockIdx.y;
  const bool is_q = head < NH;
  const int col = is_q ? head * HD : KOFF + (head - NH) * HD;
  __bf16* row = qkv + (size_t)t * QKV_N + col;
  const int d = threadIdx.x;
  float x = (float)row[d];
  float ss = x * x;
#pragma unroll
  for (int mm = 1; mm < 64; mm <<= 1) ss += __shfl_xor(ss, mm);
  __shared__ float red[2];
  __shared__ float yl[128];
  if ((d & 63) == 0) red[d >> 6] = ss;
  __syncthreads();
  float var = (red[0] + red[1]) * (1.0f / 128.0f);
  float sc = rsqrtf(var + 1e-6f);
  const float* wv = is_q ? qw : kw;
  yl[d] = x * sc * wv[d];
  __syncthreads();
  if (d < 64) {
    float x1 = yl[d], x2 = yl[d + 64];
    float c = tab[t * 128 + d];
    float sn = tab[t * 128 + 64 + d];
    row[d] = (__bf16)(x1 * c - x2 * sn);
    row[d + 64] = (__bf16)(x2 * c + x1 * sn);
  }
}

// ===== flash attention, swapped-QK^T 32x32 structure (unchanged) ===========
__device__ __forceinline__ uint32_t pkbf(float a, float b) {
  union { __bf16 h; unsigned short u; } x, y;
  x.h = (__bf16)a;
  y.h = (__bf16)b;
  return (uint32_t)x.u | ((uint32_t)y.u << 16);
}

__global__ __launch_bounds__(256, 2) void flash_attn5(const __bf16* __restrict__ qkv,
                                                      const __bf16* __restrict__ vt,
                                                      __bf16* __restrict__ attn) {
  __shared__ __attribute__((aligned(16))) __bf16 lds[32768];

  const int tid = threadIdx.x;
  const int lane = tid & 63;
  const int wave = tid >> 6;     // 0..3
  const int q5 = lane & 31;
  const int hi = lane >> 5;
  const int yy = blockIdx.x;     // 0..7
  const int kvh = yy >> 1;
  const int h = kvh * 8 + (yy & 1) * 4 + wave;
  const __bf16* Kbase = qkv + KOFF + kvh * HD;
  const __bf16* Vbase = vt + (size_t)kvh * HD * T_TOK;

  const int qt = 63 - (int)blockIdx.y;
  const int qb = qt * 32;
  const int qrow = qb + q5;
  const int nt = (qb + 32 + 63) >> 6;

  const float qscale = 0.088388347648318447f * 1.4426950408889634f;

  bf16x8 qf[8];
  {
    const __bf16* Qp = qkv + (size_t)(qb + q5) * QKV_N + h * HD + hi * 8;
#pragma unroll
    for (int k0 = 0; k0 < 8; ++k0) {
      bf16x8 q = *reinterpret_cast<const bf16x8*>(Qp + k0 * 16);
#pragma unroll
      for (int j = 0; j < 8; ++j) q[j] = (__bf16)((float)q[j] * qscale);
      qf[k0] = q;
    }
  }

  const int kc = (lane & 15) * 16;
  const int vc = (lane & 7) * 16;

#define STAGE5(b, kv00)                                                         \
  do {                                                                          \
    __bf16* kdst = lds + (b) * 8192;                                            \
    __bf16* vdst = lds + 16384 + (b) * 8192;                                    \
    _Pragma("unroll")                                                           \
    for (int i = 0; i < 4; ++i) {                                               \
      int kr = wave * 16 + i * 4 + (lane >> 4);                                 \
      int ksc = (kc ^ ((kr & 15) << 4)) >> 1;                                   \
      GLOAD_LDS16(Kbase + (size_t)((kv00) + kr) * QKV_N + ksc,                  \
                  kdst + (wave * 16 + i * 4) * 128);                            \
      int vr = wave * 32 + i * 8 + (lane >> 3);                                 \
      int vsc = (vc ^ ((vr & 7) << 4)) >> 1;                                    \
      GLOAD_LDS16(Vbase + (size_t)vr * T_TOK + (kv00) + vsc,                    \
                  vdst + (wave * 32 + i * 8) * 64);                             \
    }                                                                           \
  } while (0)

  f32x16 acc0 = {}, acc1 = {}, acc2 = {}, acc3 = {};
  float mrow = -1e30f, lrow = 0.0f;

  STAGE5(0, 0);

  int cur = 0;
  for (int t = 0; t < nt; ++t) {
    const int kv0 = t * 64;
    __builtin_amdgcn_s_barrier();
    __builtin_amdgcn_sched_barrier(0);
    if (t + 1 < nt) {
      STAGE5(cur ^ 1, kv0 + 64);
      asm volatile("s_waitcnt vmcnt(8)" ::: "memory");
    } else {
      asm volatile("s_waitcnt vmcnt(0)" ::: "memory");
    }
    __builtin_amdgcn_s_barrier();
    __builtin_amdgcn_sched_barrier(0);

    const char* Kt = (const char*)(lds + cur * 8192);
    const char* Vt = (const char*)(lds + 16384 + cur * 8192);

    f32x16 st0 = {}, st1 = {};
    __builtin_amdgcn_s_setprio(1);
#pragma unroll
    for (int k0 = 0; k0 < 8; ++k0) {
      int cS = (k0 * 32 + hi * 16) ^ ((q5 & 15) << 4);
      bf16x8 a0 = *reinterpret_cast<const bf16x8*>(Kt + q5 * 256 + cS);
      bf16x8 a1 = *reinterpret_cast<const bf16x8*>(Kt + (32 + q5) * 256 + cS);
      st0 = __builtin_amdgcn_mfma_f32_32x32x16_bf16(a0, qf[k0], st0, 0, 0, 0);
      st1 = __builtin_amdgcn_mfma_f32_32x32x16_bf16(a1, qf[k0], st1, 0, 0, 0);
    }
    __builtin_amdgcn_s_setprio(0);

    if (!(kv0 + 63 <= qb)) {
#pragma unroll
      for (int r = 0; r < 16; ++r) {
        int kp = kv0 + (r & 3) + 8 * (r >> 2) + 4 * hi;
        if (kp > qrow) st0[r] = -1e30f;
        if (kp + 32 > qrow) st1[r] = -1e30f;
      }
    }
    float mx = -1e30f;
#pragma unroll
    for (int r = 0; r < 16; ++r) mx = fmaxf(mx, fmaxf(st0[r], st1[r]));
    mx = fmaxf(mx, __shfl_xor(mx, 32));
    if (__any(mx > mrow + 8.0f)) {
      float mnew = fmaxf(mrow, mx);
      float corr = exp2f(mrow - mnew);
      lrow *= corr;
      acc0 *= corr; acc1 *= corr; acc2 *= corr; acc3 *= corr;
      mrow = mnew;
    }
    float ps = 0.0f;
#pragma unroll
    for (int r = 0; r < 16; ++r) {
      float p0 = exp2f(st0[r] - mrow);
      float p1 = exp2f(st1[r] - mrow);
      ps += p0 + p1;
      st0[r] = p0;
      st1[r] = p1;
    }
    ps += __shfl_xor(ps, 32);
    lrow += ps;

    uint32_t W0[8], W1[8];
#pragma unroll
    for (int m = 0; m < 8; ++m) {
      W0[m] = pkbf(st0[2 * m], st0[2 * m + 1]);
      W1[m] = pkbf(st1[2 * m], st1[2 * m + 1]);
    }

    const bool hib = (hi != 0);
#pragma unroll
    for (int ks = 0; ks < 4; ++ks) {
      const int j = 4 * (ks & 1);
      uint32_t wj0, wj1, wj2, wj3;
      if (ks < 2) { wj0 = W0[j]; wj1 = W0[j + 1]; wj2 = W0[j + 2]; wj3 = W0[j + 3]; }
      else        { wj0 = W1[j]; wj1 = W1[j + 1]; wj2 = W1[j + 2]; wj3 = W1[j + 3]; }
      uint32_t keepA = hib ? wj2 : wj0;
      uint32_t keepB = hib ? wj3 : wj1;
      uint32_t sendA = hib ? wj0 : wj2;
      uint32_t sendB = hib ? wj1 : wj3;
      uint32_t recvA = (uint32_t)__shfl_xor((int)sendA, 32);
      uint32_t recvB = (uint32_t)__shfl_xor((int)sendB, 32);
      union { uint32_t u[4]; bf16x8 v; } fr;
      fr.u[0] = hib ? recvA : keepA;
      fr.u[1] = hib ? recvB : keepB;
      fr.u[2] = hib ? keepA : recvA;
      fr.u[3] = hib ? keepB : recvB;
      const int cV = (ks * 32 + hi * 16) ^ ((q5 & 7) << 4);
      __builtin_amdgcn_s_setprio(1);
      bf16x8 v0 = *reinterpret_cast<const bf16x8*>(Vt + (0 * 32 + q5) * 128 + cV);
      acc0 = __builtin_amdgcn_mfma_f32_32x32x16_bf16(v0, fr.v, acc0, 0, 0, 0);
      bf16x8 v1 = *reinterpret_cast<const bf16x8*>(Vt + (1 * 32 + q5) * 128 + cV);
      acc1 = __builtin_amdgcn_mfma_f32_32x32x16_bf16(v1, fr.v, acc1, 0, 0, 0);
      bf16x8 v2 = *reinterpret_cast<const bf16x8*>(Vt + (2 * 32 + q5) * 128 + cV);
      acc2 = __builtin_amdgcn_mfma_f32_32x32x16_bf16(v2, fr.v, acc2, 0, 0, 0);
      bf16x8 v3 = *reinterpret_cast<const bf16x8*>(Vt + (3 * 32 + q5) * 128 + cV);
      acc3 = __builtin_amdgcn_mfma_f32_32x32x16_bf16(v3, fr.v, acc3, 0, 0, 0);
      __builtin_amdgcn_s_setprio(0);
    }
    cur ^= 1;
  }

  __syncthreads();
  {
    char* ob = (char*)lds + wave * 8192;
    float inv = 1.0f / lrow;
    const int swzE = (q5 & 15) << 4;
#pragma unroll
    for (int dt = 0; dt < 4; ++dt) {
      f32x16 a = dt == 0 ? acc0 : dt == 1 ? acc1 : dt == 2 ? acc2 : acc3;
#pragma unroll
      for (int t4 = 0; t4 < 4; ++t4) {
        uint2 wv;
        wv.x = pkbf(a[4 * t4] * inv, a[4 * t4 + 1] * inv);
        wv.y = pkbf(a[4 * t4 + 2] * inv, a[4 * t4 + 3] * inv);
        int d2 = (dt * 32 + 8 * t4 + 4 * hi) * 2;
        *reinterpret_cast<uint2*>(ob + q5 * 256 + (d2 ^ swzE)) = wv;
      }
    }
#pragma unroll
    for (int rr = 0; rr < 8; ++rr) {
      int idx = rr * 64 + lane;
      int q = idx >> 4;
      int cc = (idx & 15) * 16;
      bf16x8 o = *reinterpret_cast<const bf16x8*>(ob + q * 256 + (cc ^ ((q & 15) << 4)));
      *reinterpret_cast<bf16x8*>(&attn[(size_t)(qb + q) * ATT_N + h * HD + (cc >> 1)]) = o;
    }
  }
}

extern "C" void kernel_launch(void* const* d_in, const int* in_sizes, int n_in,
                              void* d_out, int out_size, void* d_ws, size_t ws_size,
                              hipStream_t stream) {
  const float* hs   = (const float*)d_in[0];
  const int*   pos  = (const int*)d_in[1];
  const float* wqkv = (const float*)d_in[2];
  const float* wo   = (const float*)d_in[3];
  const float* qw   = (const float*)d_in[4];
  const float* kw   = (const float*)d_in[5];
  float* out = (float*)d_out;

  char* p = (char*)d_ws;
  __bf16* hsb   = (__bf16*)p; p += (size_t)T_TOK * HID * 2;
  __bf16* wqkvT = (__bf16*)p; p += (size_t)QKV_N * HID * 2;
  __bf16* woT   = (__bf16*)p; p += (size_t)HID * QSZ * 2;
  __bf16* qkvb  = (__bf16*)p; p += (size_t)T_TOK * QKV_N * 2;
  __bf16* attnb = (__bf16*)p; p += (size_t)T_TOK * QSZ * 2;
  __bf16* vtb   = (__bf16*)p; p += (size_t)NKV * HD * T_TOK * 2;
  float*  ropet = (float*)p;  p += (size_t)T_TOK * HD * 4;
  float*  oprt  = (float*)p;  p += (size_t)2 * T_TOK * HID * 4;  // split-K partials 33.6MB

  cast_f32_bf16<<<(T_TOK * HID / 4) / 256, 256, 0, stream>>>(hs, hsb, T_TOK * HID / 4);
  transpose_cast<<<dim3(QKV_N / 64, HID / 64), 256, 0, stream>>>(wqkv, wqkvT, HID, QKV_N);
  transpose_cast<<<dim3(HID / 64, QSZ / 64), 256, 0, stream>>>(wo, woT, QSZ, HID);
  rope_table<<<T_TOK, 64, 0, stream>>>(pos, ropet);
  // QKV projection: grid 640 (16 M-tiles x 40 N-tiles), by-fast mapping
  gemm_v9<0><<<(QKV_N / 128) * (T_TOK / 128), 256, 0, stream>>>(
      hsb, wqkvT, qkvb, T_TOK, QKV_N, HID, HID, T_TOK / 128, 1);
  norm_rope<<<dim3(T_TOK, NH + NKV), 128, 0, stream>>>(qkvb, ropet, qw, kw);
  v_transpose<<<dim3(T_TOK / 64, HD / 64, NKV), 256, 0, stream>>>(qkvb, vtb);
  flash_attn5<<<dim3(8, 64), 256, 0, stream>>>(qkvb, vtb, attnb);
  // O projection: split-K=2, grid 512 = 2 kslices x (16x16) tiles
  gemm_v9<1><<<2 * (HID / 128) * (T_TOK / 128), 256, 0, stream>>>(
      attnb, woT, oprt, T_TOK, HID, QSZ, QSZ / 2, T_TOK / 128, 2);
  reduce2_f32<<<(T_TOK * HID / 4 + 255) / 256, 256, 0, stream>>>(
      oprt, out, T_TOK * HID / 4);
}